// Round 8
// baseline (412.084 us; speedup 1.0000x reference)
//
#include <hip/hip_runtime.h>
#include <stdint.h>

#define NB 4096
#define NS 512
#define NA 64
#define NH1 1024
#define NH2 512

typedef __attribute__((ext_vector_type(8))) short bf16x8;
typedef __attribute__((ext_vector_type(4))) float f32x4;

__device__ __forceinline__ unsigned short f2bf(float f) {
    union { float f; unsigned u; } v; v.f = f;
    return (unsigned short)((v.u + 0x8000u) >> 16);   // round-half-up bf16
}
__device__ __forceinline__ float bf2f(unsigned short h) {
    union { float f; unsigned u; } v; v.u = ((unsigned)h) << 16;
    return v.f;
}
__device__ __forceinline__ float bflo(unsigned u) {
    union { unsigned u; float f; } v; v.u = u << 16; return v.f;
}
__device__ __forceinline__ float bfhi(unsigned u) {
    union { unsigned u; float f; } v; v.u = u & 0xFFFF0000u; return v.f;
}
// truncating pack of two f32 -> bf16x2 (bias cancels in u/||u||): 1 v_perm
__device__ __forceinline__ unsigned packtrunc(float lo, float hi) {
    union { float f; unsigned u; } a, b; a.f = lo; b.f = hi;
    return __builtin_amdgcn_perm(b.u, a.u, 0x07060302u);
}
__device__ __forceinline__ void split2(float x, unsigned short& h, unsigned short& l) {
    unsigned short hh = f2bf(x);
    h = hh;
    l = f2bf(x - bf2f(hh));
}

// ---------------- P0: nb[b] = sqrt(||s_b||^2 + 1) + 1e-8 ----------------
__global__ void knorm(const float* __restrict__ S, float* __restrict__ nb) {
    int b = blockIdx.x; int l = threadIdx.x; // one wave
    const float* row = S + b * NS;
    float s = 0.f;
    for (int k = l; k < NS; k += 64) { float v = row[k]; s = fmaf(v, v, s); }
    for (int off = 32; off; off >>= 1) s += __shfl_down(s, off, 64);
    if (l == 0) nb[b] = sqrtf(s + 1.0f) + 1e-8f;
}

// ---------------- P1: W2f (frag-packed per-kc tiles, swizzled) + caT2 ----------------
// W2f short idx = ((kc*32 + c)*64 + l)*8 + j :
//   n = c*16 + (l>>2);  g = (l&3) ^ ((n>>1)&3);  value = W2[n][kc*32 + g*8 + j]
// Per-kc tile = 32*64*8 shorts = 32 KB
// caT2[at16][kc][a_loc][kk] = W1[(kc*32+kk)*576 + 512 + at16*16 + a_loc]
__global__ void kprep(const float* __restrict__ W1, const float* __restrict__ W2,
                      unsigned short* __restrict__ W2f, unsigned short* __restrict__ caT2) {
    int i = blockIdx.x * 256 + threadIdx.x;
    if (i < 524288) {
        int j = i & 7; int l = (i >> 3) & 63; int c = (i >> 9) & 31; int kc = i >> 14;
        int n = c * 16 + (l >> 2);
        int g = (l & 3) ^ ((n >> 1) & 3);
        int k = kc * 32 + g * 8 + j;
        W2f[i] = f2bf(W2[(size_t)n * NH1 + k]);
    } else {
        int j2 = i - 524288;                 // 65536 entries
        int kk = j2 & 31; int a_loc = (j2 >> 5) & 15;
        int kc = (j2 >> 9) & 31; int att = j2 >> 14;
        int o = kc * 32 + kk;
        caT2[j2] = f2bf(W1[(size_t)o * 576 + 512 + att * 16 + a_loc]);
    }
}

// ---------------- P2: Gt'[kc][b][32k] bf16 = s@W1s^T + b1*nb  (split-bf16, 3 GEMMs) ----
__global__ __launch_bounds__(256) void kgemm1(
        const float* __restrict__ Sm, const float* __restrict__ W1,
        const float* __restrict__ b1, const float* __restrict__ nb,
        unsigned short* __restrict__ Gt) {
    const int m0 = (blockIdx.x >> 3) * 128;
    const int n0 = (blockIdx.x & 7) * 128;
    __shared__ unsigned short Ah[128][40], Al[128][40], Bh[128][40], Bl[128][40];
    int t = threadIdx.x;
    int lane = t & 63, wave = t >> 6;
    int wr = wave >> 1, wc = wave & 1;
    int qd = lane >> 4, cl = lane & 15;
    int r = t >> 1, seg = t & 1;
    f32x4 acc[4][4] = {};

    for (int k0 = 0; k0 < 512; k0 += 32) {
        {
            const float4* as4 = (const float4*)(Sm + (size_t)(m0 + r) * NS + k0 + seg * 16);
            const float4* bs4 = (const float4*)(W1 + (size_t)(n0 + r) * 576 + k0 + seg * 16);
            unsigned* ah = (unsigned*)&Ah[r][seg * 16];
            unsigned* al = (unsigned*)&Al[r][seg * 16];
            unsigned* bh = (unsigned*)&Bh[r][seg * 16];
            unsigned* bl = (unsigned*)&Bl[r][seg * 16];
#pragma unroll
            for (int v = 0; v < 4; v++) {
                float4 fa = as4[v];
                unsigned short h0,h1,h2,h3,l0,l1,l2,l3;
                split2(fa.x,h0,l0); split2(fa.y,h1,l1); split2(fa.z,h2,l2); split2(fa.w,h3,l3);
                ah[v*2]   = (unsigned)h0 | ((unsigned)h1 << 16);
                ah[v*2+1] = (unsigned)h2 | ((unsigned)h3 << 16);
                al[v*2]   = (unsigned)l0 | ((unsigned)l1 << 16);
                al[v*2+1] = (unsigned)l2 | ((unsigned)l3 << 16);
                float4 fb = bs4[v];
                split2(fb.x,h0,l0); split2(fb.y,h1,l1); split2(fb.z,h2,l2); split2(fb.w,h3,l3);
                bh[v*2]   = (unsigned)h0 | ((unsigned)h1 << 16);
                bh[v*2+1] = (unsigned)h2 | ((unsigned)h3 << 16);
                bl[v*2]   = (unsigned)l0 | ((unsigned)l1 << 16);
                bl[v*2+1] = (unsigned)l2 | ((unsigned)l3 << 16);
            }
        }
        __syncthreads();
        bf16x8 a_h[4], a_l[4], b_h[4], b_l[4];
#pragma unroll
        for (int mt = 0; mt < 4; mt++) {
            a_h[mt] = *(const bf16x8*)&Ah[wr*64 + mt*16 + cl][qd*8];
            a_l[mt] = *(const bf16x8*)&Al[wr*64 + mt*16 + cl][qd*8];
        }
#pragma unroll
        for (int nt = 0; nt < 4; nt++) {
            b_h[nt] = *(const bf16x8*)&Bh[wc*64 + nt*16 + cl][qd*8];
            b_l[nt] = *(const bf16x8*)&Bl[wc*64 + nt*16 + cl][qd*8];
        }
#pragma unroll
        for (int mt = 0; mt < 4; mt++)
#pragma unroll
            for (int nt = 0; nt < 4; nt++) {
                acc[mt][nt] = __builtin_amdgcn_mfma_f32_16x16x32_bf16(a_h[mt], b_h[nt], acc[mt][nt], 0, 0, 0);
                acc[mt][nt] = __builtin_amdgcn_mfma_f32_16x16x32_bf16(a_h[mt], b_l[nt], acc[mt][nt], 0, 0, 0);
                acc[mt][nt] = __builtin_amdgcn_mfma_f32_16x16x32_bf16(a_l[mt], b_h[nt], acc[mt][nt], 0, 0, 0);
            }
        __syncthreads();
    }
#pragma unroll
    for (int mt = 0; mt < 4; mt++)
#pragma unroll
        for (int i = 0; i < 4; i++) {
            int m = m0 + wr*64 + mt*16 + qd*4 + i;
            float nbv = nb[m];
#pragma unroll
            for (int nt = 0; nt < 4; nt++) {
                int n = n0 + wc*64 + nt*16 + cl;
                float val = fmaf(b1[n], nbv, acc[mt][nt][i]);
                Gt[((size_t)(n >> 5) * NB + m) * 32 + (n & 31)] = f2bf(val);
            }
        }
}

// ---------------- Main: 256 thr, 32 rows (8a x 4b) x 512 cols, K=1024, Kc=32 ----------
// R13: 3 waves/SIMD via halved wave tile. Registers were the occupancy gate
// (128 acc + 120 arch = 248 -> 2 waves/SIMD); wave tile 32x128 cuts acc to 64
// regs -> total ~155 fits 3 waves (512/3 = 170). Block = 32 rows x 512 cols,
// 4 waves, grid 8192; each SIMD now hosts 3 waves from 3 INDEPENDENT blocks
// (independent barriers, drifting kc phases) -> 3-way coverage of every stall
// window (af latency, agen, barrier, load drains). L2 demand ~42 B/cyc/CU at
// 75% util, still under the ~56 ceiling. agen on waves 0-1 only (wave-uniform
// branch; identical per-thread code -> bit-identical sq ordering).
__global__ __launch_bounds__(256, 3) void kmain(
        const unsigned short* __restrict__ Gt,    // [32][4096][32]
        const unsigned short* __restrict__ caT2,  // [4][32][16][32]
        const unsigned short* __restrict__ W2f,   // per-kc frag-packed tiles (32 KB each)
        const float* __restrict__ nb,
        const float* __restrict__ b2, const float* __restrict__ Wq,
        const float* __restrict__ bq, float* __restrict__ out) {
    int bid = blockIdx.x;
    int at = bid & 7;             // a-octet: global a = at*8 .. at*8+7
    int bt = bid >> 3;            // 0..1023: b rows bt*4 .. bt*4+3

    __shared__ __align__(16) unsigned short As[2][32][40];  // 2 x 2.5 KB dbuf, pad +8
    __shared__ float invnh[32];
    __shared__ float qred[32][4];

    int t = threadIdx.x;          // 0..255
    int lane = t & 63, wc = t >> 6;   // wc = wave = col quarter
    int l15 = lane & 15, l4 = lane >> 4;

    // A-gen role (threads 0..127 = waves 0,1): row (t>>2) in 0..31, k-octet t&3
    int row = t >> 2, kd = t & 3;
    int ab = row >> 2, bb = row & 3;      // 8 a x 4 b
    const bool genw = (t < 128);
    const unsigned short* gG = Gt + ((size_t)(bt * 4 + bb)) * 32 + kd * 8;
    const unsigned short* gC = caT2 + (size_t)(at >> 1) * 16384
                                    + ((at & 1) * 8 + ab) * 32 + kd * 8;

    float sq = 0.f;
    f32x4 acc[2][8] = {};
    bf16x8 g_v, c_v;

    auto agen = [&](int s) {
        const unsigned* gd = (const unsigned*)&g_v;
        const unsigned* cd = (const unsigned*)&c_v;
        unsigned ow[4];
#pragma unroll
        for (int p = 0; p < 4; p++) {
            float u0 = fmaxf(bflo(gd[p]) + bflo(cd[p]), 0.f);
            float u1 = fmaxf(bfhi(gd[p]) + bfhi(cd[p]), 0.f);
            sq = fmaf(u0, u0, sq);
            sq = fmaf(u1, u1, sq);
            ow[p] = packtrunc(u0, u1);
        }
        *(bf16x8*)&As[s][row][kd * 8] = *(bf16x8*)ow;
    };

    // B frag source: de-swizzled per-lane global address, iter-invariant offset
    const int boff = (wc * 128 + l15) * 32 + ((l4 ^ ((l15 >> 1) & 3)) << 3);
    const unsigned short* gB = W2f + boff;

    bf16x8 bfrL[4], bfrH[4];

    // prologue: gen(0), bfr(kc0) loads, prefetch g/c(1)
    if (genw) {
        g_v = *(const bf16x8*)gG;
        c_v = *(const bf16x8*)gC;
        agen(0);
    }
#pragma unroll
    for (int j = 0; j < 4; j++)
        bfrL[j] = *(const bf16x8*)(gB + j * 512);
#pragma unroll
    for (int j = 0; j < 4; j++)
        bfrH[j] = *(const bf16x8*)(gB + (4 + j) * 512);
    gB += 16384;
    if (genw) {
        gG += (size_t)NB * 32;
        gC += 512;
        g_v = *(const bf16x8*)gG;
        c_v = *(const bf16x8*)gC;
    }
    asm volatile("s_waitcnt lgkmcnt(0)" ::: "memory");   // agen(0) write visible
    __builtin_amdgcn_s_barrier();
    __builtin_amdgcn_sched_barrier(0);

    for (int it = 0; it < 32; ++it) {
        int s = it & 1;

        // ---- A frags from LDS (only LDS consumer in loop) ----
        bf16x8 af[2];
#pragma unroll
        for (int mt = 0; mt < 2; mt++)
            af[mt] = *(const bf16x8*)&As[s][mt * 16 + l15][l4 * 8];

        // ---- produce next A tile + prefetch g/c(it+2) (waves 0,1 only) ----
        if (genw) {
            if (it < 31) agen(s ^ 1);
            if (it < 30) {
                gG += (size_t)NB * 32;
                gC += 512;
                g_v = *(const bf16x8*)gG;
                c_v = *(const bf16x8*)gC;
            }
        }

        // ---- MFMA on L half (bfrH(kc) still draining under this) ----
        __builtin_amdgcn_s_setprio(1);
#pragma unroll
        for (int nt = 0; nt < 4; nt++)
#pragma unroll
            for (int mt = 0; mt < 2; mt++)
                acc[mt][nt] = __builtin_amdgcn_mfma_f32_16x16x32_bf16(af[mt], bfrL[nt], acc[mt][nt], 0, 0, 0);
        __builtin_amdgcn_s_setprio(0);

        // ---- issue L'(kc+1) into L regs (WAR reuse; drains under H MFMAs) ----
        if (it < 31) {
#pragma unroll
            for (int j = 0; j < 4; j++)
                bfrL[j] = *(const bf16x8*)(gB + j * 512);
        }

        // ---- MFMA on H half (L' draining under this) ----
        __builtin_amdgcn_s_setprio(1);
#pragma unroll
        for (int nt = 0; nt < 4; nt++)
#pragma unroll
            for (int mt = 0; mt < 2; mt++)
                acc[mt][4 + nt] = __builtin_amdgcn_mfma_f32_16x16x32_bf16(af[mt], bfrH[nt], acc[mt][4 + nt], 0, 0, 0);
        __builtin_amdgcn_s_setprio(0);

        // ---- issue H'(kc+1); As dbuf flip ----
        if (it < 31) {
#pragma unroll
            for (int j = 0; j < 4; j++)
                bfrH[j] = *(const bf16x8*)(gB + (4 + j) * 512);
            gB += 16384;
            asm volatile("s_waitcnt lgkmcnt(0)" ::: "memory");  // agen write + af reads done
            __builtin_amdgcn_s_barrier();
            __builtin_amdgcn_sched_barrier(0);
        }
    }

    // ---- ||u|| per row: reduce over 4 kd threads (consecutive lanes) ----
    if (genw) {
        sq += __shfl_xor(sq, 1, 64);
        sq += __shfl_xor(sq, 2, 64);
        if (kd == 0) invnh[row] = 1.0f / (sqrtf(sq) + 1e-8f * nb[bt * 4 + bb]);
    }
    __syncthreads();

    // ---- epilogue: z = acc*invnh + b2; relu; q = sum(Wq*z) ----
    float wqv[8], b2v[8];
#pragma unroll
    for (int nt = 0; nt < 8; nt++) {
        int o = wc * 128 + nt * 16 + l15;
        wqv[nt] = Wq[o]; b2v[nt] = b2[o];
    }
#pragma unroll
    for (int mt = 0; mt < 2; mt++) {
#pragma unroll
        for (int i = 0; i < 4; i++) {
            int R = mt * 16 + l4 * 4 + i;
            float inv = invnh[R];
            float qp = 0.f;
#pragma unroll
            for (int nt = 0; nt < 8; nt++) {
                float z = fmaf(acc[mt][nt][i], inv, b2v[nt]);
                z = fmaxf(z, 0.f);
                qp = fmaf(z, wqv[nt], qp);
            }
            qp += __shfl_xor(qp, 1, 64);
            qp += __shfl_xor(qp, 2, 64);
            qp += __shfl_xor(qp, 4, 64);
            qp += __shfl_xor(qp, 8, 64);
            if (l15 == 0) qred[R][wc] = qp;
        }
    }
    __syncthreads();
    if (t < 32) {
        float qv = qred[t][0] + qred[t][1] + qred[t][2] + qred[t][3] + bq[0];
        int aa = at * 8 + (t >> 2);
        int bo = bt * 4 + (t & 3);
        out[(size_t)bo * NA + aa] = qv;
    }
}

extern "C" void kernel_launch(void* const* d_in, const int* in_sizes, int n_in,
                              void* d_out, int out_size, void* d_ws, size_t ws_size,
                              hipStream_t stream) {
    const float* states = (const float*)d_in[0];
    const float* W1     = (const float*)d_in[1];
    const float* b1     = (const float*)d_in[2];
    const float* W2     = (const float*)d_in[3];
    const float* b2     = (const float*)d_in[4];
    const float* Wq     = (const float*)d_in[5];
    const float* bq     = (const float*)d_in[6];
    float* out = (float*)d_out;

    char* ws = (char*)d_ws;
    unsigned short* Gt   = (unsigned short*)ws;                              // 8 MB
    unsigned short* W2f  = (unsigned short*)(ws + (8u << 20));               // 1 MB
    unsigned short* caT2 = (unsigned short*)(ws + (9u << 20));               // 128 KB
    float*          nbp  = (float*)(ws + (9u << 20) + (128u << 10));         // 16 KB

    knorm<<<NB, 64, 0, stream>>>(states, nbp);
    kprep<<<2304, 256, 0, stream>>>(W1, W2, W2f, caT2);
    kgemm1<<<256, 256, 0, stream>>>(states, W1, b1, nbp, Gt);
    kmain<<<8192, 256, 0, stream>>>(Gt, caT2, W2f, nbp, b2, Wq, bq, out);
}

// Round 9
// 321.316 us; speedup vs baseline: 1.2825x; 1.2825x over previous
//
#include <hip/hip_runtime.h>
#include <stdint.h>

#define NB 4096
#define NS 512
#define NA 64
#define NH1 1024
#define NH2 512

typedef __attribute__((ext_vector_type(8))) short bf16x8;
typedef __attribute__((ext_vector_type(4))) float f32x4;

__device__ __forceinline__ unsigned short f2bf(float f) {
    union { float f; unsigned u; } v; v.f = f;
    return (unsigned short)((v.u + 0x8000u) >> 16);   // round-half-up bf16
}
__device__ __forceinline__ float bf2f(unsigned short h) {
    union { float f; unsigned u; } v; v.u = ((unsigned)h) << 16;
    return v.f;
}
__device__ __forceinline__ float bflo(unsigned u) {
    union { unsigned u; float f; } v; v.u = u << 16; return v.f;
}
__device__ __forceinline__ float bfhi(unsigned u) {
    union { unsigned u; float f; } v; v.u = u & 0xFFFF0000u; return v.f;
}
// truncating pack of two f32 -> bf16x2 (bias cancels in u/||u||): 1 v_perm
__device__ __forceinline__ unsigned packtrunc(float lo, float hi) {
    union { float f; unsigned u; } a, b; a.f = lo; b.f = hi;
    return __builtin_amdgcn_perm(b.u, a.u, 0x07060302u);
}
__device__ __forceinline__ void split2(float x, unsigned short& h, unsigned short& l) {
    unsigned short hh = f2bf(x);
    h = hh;
    l = f2bf(x - bf2f(hh));
}

// ---------------- P0: nb[b] = sqrt(||s_b||^2 + 1) + 1e-8 ----------------
__global__ void knorm(const float* __restrict__ S, float* __restrict__ nb) {
    int b = blockIdx.x; int l = threadIdx.x; // one wave
    const float* row = S + b * NS;
    float s = 0.f;
    for (int k = l; k < NS; k += 64) { float v = row[k]; s = fmaf(v, v, s); }
    for (int off = 32; off; off >>= 1) s += __shfl_down(s, off, 64);
    if (l == 0) nb[b] = sqrtf(s + 1.0f) + 1e-8f;
}

// ---------------- P1: W2f (frag-packed per-kc tiles, swizzled) + caT2 ----------------
// W2f short idx = ((kc*32 + c)*64 + l)*8 + j :
//   n = c*16 + (l>>2);  g = (l&3) ^ ((n>>1)&3);  value = W2[n][kc*32 + g*8 + j]
// Per-kc tile = 32*64*8 shorts = 32 KB
// caT2[at][kc][a_loc][kk] = W1[(kc*32+kk)*576 + 512 + at*16 + a_loc]
__global__ void kprep(const float* __restrict__ W1, const float* __restrict__ W2,
                      unsigned short* __restrict__ W2f, unsigned short* __restrict__ caT2) {
    int i = blockIdx.x * 256 + threadIdx.x;
    if (i < 524288) {
        int j = i & 7; int l = (i >> 3) & 63; int c = (i >> 9) & 31; int kc = i >> 14;
        int n = c * 16 + (l >> 2);
        int g = (l & 3) ^ ((n >> 1) & 3);
        int k = kc * 32 + g * 8 + j;
        W2f[i] = f2bf(W2[(size_t)n * NH1 + k]);
    } else {
        int j2 = i - 524288;                 // 65536 entries
        int kk = j2 & 31; int a_loc = (j2 >> 5) & 15;
        int kc = (j2 >> 9) & 31; int att = j2 >> 14;
        int o = kc * 32 + kk;
        caT2[j2] = f2bf(W1[(size_t)o * 576 + 512 + att * 16 + a_loc]);
    }
}

// ---------------- P2: Gt'[kc][b][32k] bf16 = s@W1s^T + b1*nb  (split-bf16, 3 GEMMs) ----
__global__ __launch_bounds__(256) void kgemm1(
        const float* __restrict__ Sm, const float* __restrict__ W1,
        const float* __restrict__ b1, const float* __restrict__ nb,
        unsigned short* __restrict__ Gt) {
    const int m0 = (blockIdx.x >> 3) * 128;
    const int n0 = (blockIdx.x & 7) * 128;
    __shared__ unsigned short Ah[128][40], Al[128][40], Bh[128][40], Bl[128][40];
    int t = threadIdx.x;
    int lane = t & 63, wave = t >> 6;
    int wr = wave >> 1, wc = wave & 1;
    int qd = lane >> 4, cl = lane & 15;
    int r = t >> 1, seg = t & 1;
    f32x4 acc[4][4] = {};

    for (int k0 = 0; k0 < 512; k0 += 32) {
        {
            const float4* as4 = (const float4*)(Sm + (size_t)(m0 + r) * NS + k0 + seg * 16);
            const float4* bs4 = (const float4*)(W1 + (size_t)(n0 + r) * 576 + k0 + seg * 16);
            unsigned* ah = (unsigned*)&Ah[r][seg * 16];
            unsigned* al = (unsigned*)&Al[r][seg * 16];
            unsigned* bh = (unsigned*)&Bh[r][seg * 16];
            unsigned* bl = (unsigned*)&Bl[r][seg * 16];
#pragma unroll
            for (int v = 0; v < 4; v++) {
                float4 fa = as4[v];
                unsigned short h0,h1,h2,h3,l0,l1,l2,l3;
                split2(fa.x,h0,l0); split2(fa.y,h1,l1); split2(fa.z,h2,l2); split2(fa.w,h3,l3);
                ah[v*2]   = (unsigned)h0 | ((unsigned)h1 << 16);
                ah[v*2+1] = (unsigned)h2 | ((unsigned)h3 << 16);
                al[v*2]   = (unsigned)l0 | ((unsigned)l1 << 16);
                al[v*2+1] = (unsigned)l2 | ((unsigned)l3 << 16);
                float4 fb = bs4[v];
                split2(fb.x,h0,l0); split2(fb.y,h1,l1); split2(fb.z,h2,l2); split2(fb.w,h3,l3);
                bh[v*2]   = (unsigned)h0 | ((unsigned)h1 << 16);
                bh[v*2+1] = (unsigned)h2 | ((unsigned)h3 << 16);
                bl[v*2]   = (unsigned)l0 | ((unsigned)l1 << 16);
                bl[v*2+1] = (unsigned)l2 | ((unsigned)l3 << 16);
            }
        }
        __syncthreads();
        bf16x8 a_h[4], a_l[4], b_h[4], b_l[4];
#pragma unroll
        for (int mt = 0; mt < 4; mt++) {
            a_h[mt] = *(const bf16x8*)&Ah[wr*64 + mt*16 + cl][qd*8];
            a_l[mt] = *(const bf16x8*)&Al[wr*64 + mt*16 + cl][qd*8];
        }
#pragma unroll
        for (int nt = 0; nt < 4; nt++) {
            b_h[nt] = *(const bf16x8*)&Bh[wc*64 + nt*16 + cl][qd*8];
            b_l[nt] = *(const bf16x8*)&Bl[wc*64 + nt*16 + cl][qd*8];
        }
#pragma unroll
        for (int mt = 0; mt < 4; mt++)
#pragma unroll
            for (int nt = 0; nt < 4; nt++) {
                acc[mt][nt] = __builtin_amdgcn_mfma_f32_16x16x32_bf16(a_h[mt], b_h[nt], acc[mt][nt], 0, 0, 0);
                acc[mt][nt] = __builtin_amdgcn_mfma_f32_16x16x32_bf16(a_h[mt], b_l[nt], acc[mt][nt], 0, 0, 0);
                acc[mt][nt] = __builtin_amdgcn_mfma_f32_16x16x32_bf16(a_l[mt], b_h[nt], acc[mt][nt], 0, 0, 0);
            }
        __syncthreads();
    }
#pragma unroll
    for (int mt = 0; mt < 4; mt++)
#pragma unroll
        for (int i = 0; i < 4; i++) {
            int m = m0 + wr*64 + mt*16 + qd*4 + i;
            float nbv = nb[m];
#pragma unroll
            for (int nt = 0; nt < 4; nt++) {
                int n = n0 + wc*64 + nt*16 + cl;
                float val = fmaf(b1[n], nbv, acc[mt][nt][i]);
                Gt[((size_t)(n >> 5) * NB + m) * 32 + (n & 31)] = f2bf(val);
            }
        }
}

// ---------------- Main: 256 thr, 64 rows (16a x 4b) x 512 cols, K=1024, Kc=32 ----------
// R14 = R12 base (64-row 4-wave blocks, grid 4096, global-B bfrL/H pipeline,
// best 255 us) + As RING with barrier every 4 iters. R13 lesson: per-iter
// overhead is per-WAVE, MFMA content scales with tile height -> keep the fat
// 64-row tile; attack the 613 cyc/slot exposure instead. The per-kc full
// rendezvous + lgkmcnt(0) re-phase-locked the block's 4 waves every iter.
// Now: produce-lead 4 (agen at iter it writes tile it+4 into slot (it+4)&7;
// prologue fills tiles 0..3), consume slot it&7, s_barrier only at it%4==0.
// Safety: tile j is produced at iter j-4 (previous window, drained by the
// window barrier); max intra-window drift 3 < ring 8 - lead 4 -> no
// overwrite race. Waves slip up to 4 kc against each other: intra-block
// anti-phasing covers af latency + L2 spikes; 3/4 of barrier cost gone.
// Register cost zero (same g/c pair, af, bfr, acc); LDS 41 KB (regs bind).
__global__ __launch_bounds__(256, 2) void kmain(
        const unsigned short* __restrict__ Gt,    // [32][4096][32]
        const unsigned short* __restrict__ caT2,  // [4][32][16][32]
        const unsigned short* __restrict__ W2f,   // per-kc frag-packed tiles (32 KB each)
        const float* __restrict__ nb,
        const float* __restrict__ b2, const float* __restrict__ Wq,
        const float* __restrict__ bq, float* __restrict__ out) {
    int bid = blockIdx.x;
    int at = bid & 3;
    int bt = bid >> 2;            // 0..1023, covers b rows bt*4 .. bt*4+3

    __shared__ __align__(16) unsigned short As[8][64][40];  // 8-slot ring, 40 KB, pad +8
    __shared__ float invnh[64];
    __shared__ float qred[64][4];

    int t = threadIdx.x;          // 0..255
    int lane = t & 63, wc = t >> 6;   // wc = wave = col quarter
    int l15 = lane & 15, l4 = lane >> 4;

    // A-gen role: thread owns row (t>>2), k-octet (t&3); 8 elements/iter
    int row = t >> 2, kd = t & 3;     // row 0..63
    int ab = row >> 2, bb = row & 3;  // 16 a x 4 b
    const unsigned short* gG = Gt + ((size_t)(bt * 4 + bb)) * 32 + kd * 8;
    const unsigned short* gC = caT2 + (size_t)at * 16384 + ab * 32 + kd * 8;

    float sq = 0.f;
    f32x4 acc[4][8] = {};
    bf16x8 g_v, c_v;

    auto agen = [&](int slot) {
        const unsigned* gd = (const unsigned*)&g_v;
        const unsigned* cd = (const unsigned*)&c_v;
        unsigned ow[4];
#pragma unroll
        for (int p = 0; p < 4; p++) {
            float u0 = fmaxf(bflo(gd[p]) + bflo(cd[p]), 0.f);
            float u1 = fmaxf(bfhi(gd[p]) + bfhi(cd[p]), 0.f);
            sq = fmaf(u0, u0, sq);
            sq = fmaf(u1, u1, sq);
            ow[p] = packtrunc(u0, u1);
        }
        *(bf16x8*)&As[slot][row][kd * 8] = *(bf16x8*)ow;
    };

    // B frag source: de-swizzled per-lane global address, iter-invariant offset
    const int boff = (wc * 128 + l15) * 32 + ((l4 ^ ((l15 >> 1) & 3)) << 3);
    const unsigned short* gB = W2f + boff;

    bf16x8 bfrL[4], bfrH[4];

    // ---- prologue: produce tiles 0..3 into ring slots 0..3; leave g/c = tile 4 ----
    g_v = *(const bf16x8*)gG;
    c_v = *(const bf16x8*)gC;
#pragma unroll
    for (int p = 0; p < 4; ++p) {
        agen(p);                       // tile p -> slot p (ascending kc: sq order preserved)
        gG += (size_t)NB * 32;
        gC += 512;
        g_v = *(const bf16x8*)gG;      // tile p+1 (ends with tile 4)
        c_v = *(const bf16x8*)gC;
    }
    // bfr(kc0)
#pragma unroll
    for (int j = 0; j < 4; j++)
        bfrL[j] = *(const bf16x8*)(gB + j * 512);
#pragma unroll
    for (int j = 0; j < 4; j++)
        bfrH[j] = *(const bf16x8*)(gB + (4 + j) * 512);
    gB += 16384;

    for (int it = 0; it < 32; ++it) {
        // ---- window barrier: publish tiles produced in previous window ----
        if ((it & 3) == 0) {
            asm volatile("s_waitcnt lgkmcnt(0)" ::: "memory");  // drain own agen writes
            __builtin_amdgcn_s_barrier();
            __builtin_amdgcn_sched_barrier(0);
        }
        int rs = it & 7;

        // ---- A frags from ring slot ----
        bf16x8 af[4];
#pragma unroll
        for (int mt = 0; mt < 4; mt++)
            af[mt] = *(const bf16x8*)&As[rs][mt * 16 + l15][l4 * 8];

        // ---- produce tile it+4 into slot (it+4)&7; prefetch g/c(it+5) ----
        if (it < 28) agen((it + 4) & 7);
        if (it < 27) {
            gG += (size_t)NB * 32;
            gC += 512;
            g_v = *(const bf16x8*)gG;
            c_v = *(const bf16x8*)gC;
        }

        // ---- MFMA on L half (bfrH(kc) still draining under this) ----
        __builtin_amdgcn_s_setprio(1);
#pragma unroll
        for (int nt = 0; nt < 4; nt++)
#pragma unroll
            for (int mt = 0; mt < 4; mt++)
                acc[mt][nt] = __builtin_amdgcn_mfma_f32_16x16x32_bf16(af[mt], bfrL[nt], acc[mt][nt], 0, 0, 0);
        __builtin_amdgcn_s_setprio(0);

        // ---- issue L'(kc+1) into L regs (WAR reuse; drains under H MFMAs) ----
        if (it < 31) {
#pragma unroll
            for (int j = 0; j < 4; j++)
                bfrL[j] = *(const bf16x8*)(gB + j * 512);
        }

        // ---- MFMA on H half (L' draining under this) ----
        __builtin_amdgcn_s_setprio(1);
#pragma unroll
        for (int nt = 0; nt < 4; nt++)
#pragma unroll
            for (int mt = 0; mt < 4; mt++)
                acc[mt][4 + nt] = __builtin_amdgcn_mfma_f32_16x16x32_bf16(af[mt], bfrH[nt], acc[mt][4 + nt], 0, 0, 0);
        __builtin_amdgcn_s_setprio(0);

        // ---- issue H'(kc+1) ----
        if (it < 31) {
#pragma unroll
            for (int j = 0; j < 4; j++)
                bfrH[j] = *(const bf16x8*)(gB + (4 + j) * 512);
            gB += 16384;
        }
    }

    // ---- ||u|| per row: reduce over 4 kd threads (consecutive lanes) ----
    sq += __shfl_xor(sq, 1, 64);
    sq += __shfl_xor(sq, 2, 64);
    if (kd == 0) invnh[row] = 1.0f / (sqrtf(sq) + 1e-8f * nb[bt * 4 + bb]);
    __syncthreads();

    // ---- epilogue: z = acc*invnh + b2; relu; q = sum(Wq*z) ----
    float wqv[8], b2v[8];
#pragma unroll
    for (int nt = 0; nt < 8; nt++) {
        int o = wc * 128 + nt * 16 + l15;
        wqv[nt] = Wq[o]; b2v[nt] = b2[o];
    }
#pragma unroll
    for (int mt = 0; mt < 4; mt++) {
#pragma unroll
        for (int i = 0; i < 4; i++) {
            int R = mt * 16 + l4 * 4 + i;
            float inv = invnh[R];
            float qp = 0.f;
#pragma unroll
            for (int nt = 0; nt < 8; nt++) {
                float z = fmaf(acc[mt][nt][i], inv, b2v[nt]);
                z = fmaxf(z, 0.f);
                qp = fmaf(z, wqv[nt], qp);
            }
            qp += __shfl_xor(qp, 1, 64);
            qp += __shfl_xor(qp, 2, 64);
            qp += __shfl_xor(qp, 4, 64);
            qp += __shfl_xor(qp, 8, 64);
            if (l15 == 0) qred[R][wc] = qp;
        }
    }
    __syncthreads();
    if (t < 64) {
        float qv = qred[t][0] + qred[t][1] + qred[t][2] + qred[t][3] + bq[0];
        int aa = at * 16 + (t >> 2);
        int bo = bt * 4 + (t & 3);
        out[(size_t)bo * NA + aa] = qv;
    }
}

extern "C" void kernel_launch(void* const* d_in, const int* in_sizes, int n_in,
                              void* d_out, int out_size, void* d_ws, size_t ws_size,
                              hipStream_t stream) {
    const float* states = (const float*)d_in[0];
    const float* W1     = (const float*)d_in[1];
    const float* b1     = (const float*)d_in[2];
    const float* W2     = (const float*)d_in[3];
    const float* b2     = (const float*)d_in[4];
    const float* Wq     = (const float*)d_in[5];
    const float* bq     = (const float*)d_in[6];
    float* out = (float*)d_out;

    char* ws = (char*)d_ws;
    unsigned short* Gt   = (unsigned short*)ws;                              // 8 MB
    unsigned short* W2f  = (unsigned short*)(ws + (8u << 20));               // 1 MB
    unsigned short* caT2 = (unsigned short*)(ws + (9u << 20));               // 128 KB
    float*          nbp  = (float*)(ws + (9u << 20) + (128u << 10));         // 16 KB

    knorm<<<NB, 64, 0, stream>>>(states, nbp);
    kprep<<<2304, 256, 0, stream>>>(W1, W2, W2f, caT2);
    kgemm1<<<256, 256, 0, stream>>>(states, W1, b1, nbp, Gt);
    kmain<<<4096, 256, 0, stream>>>(Gt, caT2, W2f, nbp, b2, Wq, bq, out);
}

// Round 10
// 317.888 us; speedup vs baseline: 1.2963x; 1.0108x over previous
//
#include <hip/hip_runtime.h>
#include <stdint.h>

#define NB 4096
#define NS 512
#define NA 64
#define NH1 1024
#define NH2 512

typedef __attribute__((ext_vector_type(8))) short bf16x8;
typedef __attribute__((ext_vector_type(4))) float f32x4;

__device__ __forceinline__ unsigned short f2bf(float f) {
    union { float f; unsigned u; } v; v.f = f;
    return (unsigned short)((v.u + 0x8000u) >> 16);   // round-half-up bf16
}
__device__ __forceinline__ float bf2f(unsigned short h) {
    union { float f; unsigned u; } v; v.u = ((unsigned)h) << 16;
    return v.f;
}
__device__ __forceinline__ float bflo(unsigned u) {
    union { unsigned u; float f; } v; v.u = u << 16; return v.f;
}
__device__ __forceinline__ float bfhi(unsigned u) {
    union { unsigned u; float f; } v; v.u = u & 0xFFFF0000u; return v.f;
}
// truncating pack of two f32 -> bf16x2 (bias cancels in u/||u||): 1 v_perm
__device__ __forceinline__ unsigned packtrunc(float lo, float hi) {
    union { float f; unsigned u; } a, b; a.f = lo; b.f = hi;
    return __builtin_amdgcn_perm(b.u, a.u, 0x07060302u);
}
__device__ __forceinline__ void split2(float x, unsigned short& h, unsigned short& l) {
    unsigned short hh = f2bf(x);
    h = hh;
    l = f2bf(x - bf2f(hh));
}

// ---------------- P0: nb[b] = sqrt(||s_b||^2 + 1) + 1e-8 ----------------
__global__ void knorm(const float* __restrict__ S, float* __restrict__ nb) {
    int b = blockIdx.x; int l = threadIdx.x; // one wave
    const float* row = S + b * NS;
    float s = 0.f;
    for (int k = l; k < NS; k += 64) { float v = row[k]; s = fmaf(v, v, s); }
    for (int off = 32; off; off >>= 1) s += __shfl_down(s, off, 64);
    if (l == 0) nb[b] = sqrtf(s + 1.0f) + 1e-8f;
}

// ---------------- P1: W2f (frag-packed per-kc tiles, swizzled) + caT2 ----------------
// W2f short idx = ((kc*32 + c)*64 + l)*8 + j :
//   n = c*16 + (l>>2);  g = (l&3) ^ ((n>>1)&3);  value = W2[n][kc*32 + g*8 + j]
// Per-kc tile = 32*64*8 shorts = 32 KB
// caT2[at][kc][a_loc][kk] = W1[(kc*32+kk)*576 + 512 + at*16 + a_loc]
__global__ void kprep(const float* __restrict__ W1, const float* __restrict__ W2,
                      unsigned short* __restrict__ W2f, unsigned short* __restrict__ caT2) {
    int i = blockIdx.x * 256 + threadIdx.x;
    if (i < 524288) {
        int j = i & 7; int l = (i >> 3) & 63; int c = (i >> 9) & 31; int kc = i >> 14;
        int n = c * 16 + (l >> 2);
        int g = (l & 3) ^ ((n >> 1) & 3);
        int k = kc * 32 + g * 8 + j;
        W2f[i] = f2bf(W2[(size_t)n * NH1 + k]);
    } else {
        int j2 = i - 524288;                 // 65536 entries
        int kk = j2 & 31; int a_loc = (j2 >> 5) & 15;
        int kc = (j2 >> 9) & 31; int att = j2 >> 14;
        int o = kc * 32 + kk;
        caT2[j2] = f2bf(W1[(size_t)o * 576 + 512 + att * 16 + a_loc]);
    }
}

// ---------------- P2: Gt'[kc][b][32k] bf16 = s@W1s^T + b1*nb  (split-bf16, 3 GEMMs) ----
// R15: re-tiled 128x128 -> 64x64 (grid 1024 = 64 Mt x 16 Nt, 4 blocks/CU).
// Old config was 256 blocks = 1 block/CU = 1 wave/SIMD: the VALU-heavy split2
// staging, LDS reads and MFMA ran serially with zero co-resident work (the
// same phase-locking disease fixed in kmain at R12). Now each SIMD hosts 4
// waves from 4 INDEPENDENT blocks -> staging/MFMA cross-cover. Same k0 order,
// same 3-product sequence, same split2 math -> Gt is BIT-IDENTICAL.
__global__ __launch_bounds__(256) void kgemm1(
        const float* __restrict__ Sm, const float* __restrict__ W1,
        const float* __restrict__ b1, const float* __restrict__ nb,
        unsigned short* __restrict__ Gt) {
    const int m0 = (blockIdx.x >> 4) * 64;   // 64 M-tiles
    const int n0 = (blockIdx.x & 15) * 64;   // 16 N-tiles
    __shared__ unsigned short Ah[64][40], Al[64][40], Bh[64][40], Bl[64][40];
    int t = threadIdx.x;
    int lane = t & 63, wave = t >> 6;
    int wr = wave >> 1, wc = wave & 1;       // 2x2 waves of 32x32 tiles
    int qd = lane >> 4, cl = lane & 15;
    int r = t >> 2, seg = t & 3;             // 4 threads/row, 8 floats each
    f32x4 acc[2][2] = {};

    for (int k0 = 0; k0 < 512; k0 += 32) {
        {
            const float4* as4 = (const float4*)(Sm + (size_t)(m0 + r) * NS + k0 + seg * 8);
            const float4* bs4 = (const float4*)(W1 + (size_t)(n0 + r) * 576 + k0 + seg * 8);
            unsigned* ah = (unsigned*)&Ah[r][seg * 8];
            unsigned* al = (unsigned*)&Al[r][seg * 8];
            unsigned* bh = (unsigned*)&Bh[r][seg * 8];
            unsigned* bl = (unsigned*)&Bl[r][seg * 8];
#pragma unroll
            for (int v = 0; v < 2; v++) {
                float4 fa = as4[v];
                unsigned short h0,h1,h2,h3,l0,l1,l2,l3;
                split2(fa.x,h0,l0); split2(fa.y,h1,l1); split2(fa.z,h2,l2); split2(fa.w,h3,l3);
                ah[v*2]   = (unsigned)h0 | ((unsigned)h1 << 16);
                ah[v*2+1] = (unsigned)h2 | ((unsigned)h3 << 16);
                al[v*2]   = (unsigned)l0 | ((unsigned)l1 << 16);
                al[v*2+1] = (unsigned)l2 | ((unsigned)l3 << 16);
                float4 fb = bs4[v];
                split2(fb.x,h0,l0); split2(fb.y,h1,l1); split2(fb.z,h2,l2); split2(fb.w,h3,l3);
                bh[v*2]   = (unsigned)h0 | ((unsigned)h1 << 16);
                bh[v*2+1] = (unsigned)h2 | ((unsigned)h3 << 16);
                bl[v*2]   = (unsigned)l0 | ((unsigned)l1 << 16);
                bl[v*2+1] = (unsigned)l2 | ((unsigned)l3 << 16);
            }
        }
        __syncthreads();
        bf16x8 a_h[2], a_l[2], b_h[2], b_l[2];
#pragma unroll
        for (int mt = 0; mt < 2; mt++) {
            a_h[mt] = *(const bf16x8*)&Ah[wr*32 + mt*16 + cl][qd*8];
            a_l[mt] = *(const bf16x8*)&Al[wr*32 + mt*16 + cl][qd*8];
        }
#pragma unroll
        for (int nt = 0; nt < 2; nt++) {
            b_h[nt] = *(const bf16x8*)&Bh[wc*32 + nt*16 + cl][qd*8];
            b_l[nt] = *(const bf16x8*)&Bl[wc*32 + nt*16 + cl][qd*8];
        }
#pragma unroll
        for (int mt = 0; mt < 2; mt++)
#pragma unroll
            for (int nt = 0; nt < 2; nt++) {
                acc[mt][nt] = __builtin_amdgcn_mfma_f32_16x16x32_bf16(a_h[mt], b_h[nt], acc[mt][nt], 0, 0, 0);
                acc[mt][nt] = __builtin_amdgcn_mfma_f32_16x16x32_bf16(a_h[mt], b_l[nt], acc[mt][nt], 0, 0, 0);
                acc[mt][nt] = __builtin_amdgcn_mfma_f32_16x16x32_bf16(a_l[mt], b_h[nt], acc[mt][nt], 0, 0, 0);
            }
        __syncthreads();
    }
#pragma unroll
    for (int mt = 0; mt < 2; mt++)
#pragma unroll
        for (int i = 0; i < 4; i++) {
            int m = m0 + wr*32 + mt*16 + qd*4 + i;
            float nbv = nb[m];
#pragma unroll
            for (int nt = 0; nt < 2; nt++) {
                int n = n0 + wc*32 + nt*16 + cl;
                float val = fmaf(b1[n], nbv, acc[mt][nt][i]);
                Gt[((size_t)(n >> 5) * NB + m) * 32 + (n & 31)] = f2bf(val);
            }
        }
}

// ---------------- Main: 256 thr, 64 rows (16a x 4b) x 512 cols, K=1024, Kc=32 ----------
// R14 (UNCHANGED this round, 244 us): 64-row 4-wave blocks, grid 4096,
// global-B bfrL/H register pipeline, As 8-slot ring with barrier every 4 iters
// (produce-lead 4: agen at iter it writes tile it+4 into slot (it+4)&7).
__global__ __launch_bounds__(256, 2) void kmain(
        const unsigned short* __restrict__ Gt,    // [32][4096][32]
        const unsigned short* __restrict__ caT2,  // [4][32][16][32]
        const unsigned short* __restrict__ W2f,   // per-kc frag-packed tiles (32 KB each)
        const float* __restrict__ nb,
        const float* __restrict__ b2, const float* __restrict__ Wq,
        const float* __restrict__ bq, float* __restrict__ out) {
    int bid = blockIdx.x;
    int at = bid & 3;
    int bt = bid >> 2;            // 0..1023, covers b rows bt*4 .. bt*4+3

    __shared__ __align__(16) unsigned short As[8][64][40];  // 8-slot ring, 40 KB, pad +8
    __shared__ float invnh[64];
    __shared__ float qred[64][4];

    int t = threadIdx.x;          // 0..255
    int lane = t & 63, wc = t >> 6;   // wc = wave = col quarter
    int l15 = lane & 15, l4 = lane >> 4;

    // A-gen role: thread owns row (t>>2), k-octet (t&3); 8 elements/iter
    int row = t >> 2, kd = t & 3;     // row 0..63
    int ab = row >> 2, bb = row & 3;  // 16 a x 4 b
    const unsigned short* gG = Gt + ((size_t)(bt * 4 + bb)) * 32 + kd * 8;
    const unsigned short* gC = caT2 + (size_t)at * 16384 + ab * 32 + kd * 8;

    float sq = 0.f;
    f32x4 acc[4][8] = {};
    bf16x8 g_v, c_v;

    auto agen = [&](int slot) {
        const unsigned* gd = (const unsigned*)&g_v;
        const unsigned* cd = (const unsigned*)&c_v;
        unsigned ow[4];
#pragma unroll
        for (int p = 0; p < 4; p++) {
            float u0 = fmaxf(bflo(gd[p]) + bflo(cd[p]), 0.f);
            float u1 = fmaxf(bfhi(gd[p]) + bfhi(cd[p]), 0.f);
            sq = fmaf(u0, u0, sq);
            sq = fmaf(u1, u1, sq);
            ow[p] = packtrunc(u0, u1);
        }
        *(bf16x8*)&As[slot][row][kd * 8] = *(bf16x8*)ow;
    };

    // B frag source: de-swizzled per-lane global address, iter-invariant offset
    const int boff = (wc * 128 + l15) * 32 + ((l4 ^ ((l15 >> 1) & 3)) << 3);
    const unsigned short* gB = W2f + boff;

    bf16x8 bfrL[4], bfrH[4];

    // ---- prologue: produce tiles 0..3 into ring slots 0..3; leave g/c = tile 4 ----
    g_v = *(const bf16x8*)gG;
    c_v = *(const bf16x8*)gC;
#pragma unroll
    for (int p = 0; p < 4; ++p) {
        agen(p);                       // tile p -> slot p (ascending kc: sq order preserved)
        gG += (size_t)NB * 32;
        gC += 512;
        g_v = *(const bf16x8*)gG;      // tile p+1 (ends with tile 4)
        c_v = *(const bf16x8*)gC;
    }
    // bfr(kc0)
#pragma unroll
    for (int j = 0; j < 4; j++)
        bfrL[j] = *(const bf16x8*)(gB + j * 512);
#pragma unroll
    for (int j = 0; j < 4; j++)
        bfrH[j] = *(const bf16x8*)(gB + (4 + j) * 512);
    gB += 16384;

    for (int it = 0; it < 32; ++it) {
        // ---- window barrier: publish tiles produced in previous window ----
        if ((it & 3) == 0) {
            asm volatile("s_waitcnt lgkmcnt(0)" ::: "memory");  // drain own agen writes
            __builtin_amdgcn_s_barrier();
            __builtin_amdgcn_sched_barrier(0);
        }
        int rs = it & 7;

        // ---- A frags from ring slot ----
        bf16x8 af[4];
#pragma unroll
        for (int mt = 0; mt < 4; mt++)
            af[mt] = *(const bf16x8*)&As[rs][mt * 16 + l15][l4 * 8];

        // ---- produce tile it+4 into slot (it+4)&7; prefetch g/c(it+5) ----
        if (it < 28) agen((it + 4) & 7);
        if (it < 27) {
            gG += (size_t)NB * 32;
            gC += 512;
            g_v = *(const bf16x8*)gG;
            c_v = *(const bf16x8*)gC;
        }

        // ---- MFMA on L half (bfrH(kc) still draining under this) ----
        __builtin_amdgcn_s_setprio(1);
#pragma unroll
        for (int nt = 0; nt < 4; nt++)
#pragma unroll
            for (int mt = 0; mt < 4; mt++)
                acc[mt][nt] = __builtin_amdgcn_mfma_f32_16x16x32_bf16(af[mt], bfrL[nt], acc[mt][nt], 0, 0, 0);
        __builtin_amdgcn_s_setprio(0);

        // ---- issue L'(kc+1) into L regs (WAR reuse; drains under H MFMAs) ----
        if (it < 31) {
#pragma unroll
            for (int j = 0; j < 4; j++)
                bfrL[j] = *(const bf16x8*)(gB + j * 512);
        }

        // ---- MFMA on H half (L' draining under this) ----
        __builtin_amdgcn_s_setprio(1);
#pragma unroll
        for (int nt = 0; nt < 4; nt++)
#pragma unroll
            for (int mt = 0; mt < 4; mt++)
                acc[mt][4 + nt] = __builtin_amdgcn_mfma_f32_16x16x32_bf16(af[mt], bfrH[nt], acc[mt][4 + nt], 0, 0, 0);
        __builtin_amdgcn_s_setprio(0);

        // ---- issue H'(kc+1) ----
        if (it < 31) {
#pragma unroll
            for (int j = 0; j < 4; j++)
                bfrH[j] = *(const bf16x8*)(gB + (4 + j) * 512);
            gB += 16384;
        }
    }

    // ---- ||u|| per row: reduce over 4 kd threads (consecutive lanes) ----
    sq += __shfl_xor(sq, 1, 64);
    sq += __shfl_xor(sq, 2, 64);
    if (kd == 0) invnh[row] = 1.0f / (sqrtf(sq) + 1e-8f * nb[bt * 4 + bb]);
    __syncthreads();

    // ---- epilogue: z = acc*invnh + b2; relu; q = sum(Wq*z) ----
    float wqv[8], b2v[8];
#pragma unroll
    for (int nt = 0; nt < 8; nt++) {
        int o = wc * 128 + nt * 16 + l15;
        wqv[nt] = Wq[o]; b2v[nt] = b2[o];
    }
#pragma unroll
    for (int mt = 0; mt < 4; mt++) {
#pragma unroll
        for (int i = 0; i < 4; i++) {
            int R = mt * 16 + l4 * 4 + i;
            float inv = invnh[R];
            float qp = 0.f;
#pragma unroll
            for (int nt = 0; nt < 8; nt++) {
                float z = fmaf(acc[mt][nt][i], inv, b2v[nt]);
                z = fmaxf(z, 0.f);
                qp = fmaf(z, wqv[nt], qp);
            }
            qp += __shfl_xor(qp, 1, 64);
            qp += __shfl_xor(qp, 2, 64);
            qp += __shfl_xor(qp, 4, 64);
            qp += __shfl_xor(qp, 8, 64);
            if (l15 == 0) qred[R][wc] = qp;
        }
    }
    __syncthreads();
    if (t < 64) {
        float qv = qred[t][0] + qred[t][1] + qred[t][2] + qred[t][3] + bq[0];
        int aa = at * 16 + (t >> 2);
        int bo = bt * 4 + (t & 3);
        out[(size_t)bo * NA + aa] = qv;
    }
}

extern "C" void kernel_launch(void* const* d_in, const int* in_sizes, int n_in,
                              void* d_out, int out_size, void* d_ws, size_t ws_size,
                              hipStream_t stream) {
    const float* states = (const float*)d_in[0];
    const float* W1     = (const float*)d_in[1];
    const float* b1     = (const float*)d_in[2];
    const float* W2     = (const float*)d_in[3];
    const float* b2     = (const float*)d_in[4];
    const float* Wq     = (const float*)d_in[5];
    const float* bq     = (const float*)d_in[6];
    float* out = (float*)d_out;

    char* ws = (char*)d_ws;
    unsigned short* Gt   = (unsigned short*)ws;                              // 8 MB
    unsigned short* W2f  = (unsigned short*)(ws + (8u << 20));               // 1 MB
    unsigned short* caT2 = (unsigned short*)(ws + (9u << 20));               // 128 KB
    float*          nbp  = (float*)(ws + (9u << 20) + (128u << 10));         // 16 KB

    knorm<<<NB, 64, 0, stream>>>(states, nbp);
    kprep<<<2304, 256, 0, stream>>>(W1, W2, W2f, caT2);
    kgemm1<<<1024, 256, 0, stream>>>(states, W1, b1, nbp, Gt);
    kmain<<<4096, 256, 0, stream>>>(Gt, caT2, W2f, nbp, b2, Wq, bq, out);
}